// Round 8
// baseline (833.946 us; speedup 1.0000x reference)
//
#include <hip/hip_runtime.h>
#include <hip/hip_bf16.h>
#include <math.h>

// ASTGCN block, MI355X. Round 14: k_gemm3 occupancy fix. r13 counters:
// FETCH fixed (356->89MB) but Occupancy 10.9% — LDS 53248 (epilogue A_th
// [256][104]) allows only 2 blocks/CU, so the per-K-step vmcnt(0)+barrier
// drain has no other block to hide behind (Mfma 18.8%, VALU 24.7%, HBM 10%:
// all idle). Epilogue now half-split through A_th[128][104] (26624 B, fits
// in the dead staging region) -> LDS 40960; __launch_bounds__(256,4) pins
// VGPR<=128 so 4 blocks/CU co-reside. Values bit-identical.

namespace {

constexpr int B = 16, N = 1024, F = 32, T = 24, CC = 64, CT = 64;
constexpr int FT = F * T;     // 768
constexpr int CTT = CT * T;   // 1536
constexpr int NSEG = 8;       // softmax n-segments

using f32x4  = __attribute__((ext_vector_type(4))) float;
using short8 = __attribute__((ext_vector_type(8))) short;

__device__ __forceinline__ float b2f(__hip_bfloat16 v) { return __bfloat162float(v); }
__device__ __forceinline__ unsigned short f2bu(float x) {   // fp32 -> bf16 bits, RNE
  union { float f; unsigned u; } c; c.f = x;
  unsigned u = c.u;
  return (unsigned short)((u + 0x7FFFu + ((u >> 16) & 1u)) >> 16);
}
__device__ __forceinline__ float us2f(unsigned short u) {   // bf16 bits -> fp32
  union { unsigned u; float f; } c; c.u = ((unsigned)u) << 16; return c.f;
}
__device__ __forceinline__ void gload16(const void* g, void* l) {
  __builtin_amdgcn_global_load_lds(
      (const __attribute__((address_space(1))) unsigned int*)g,
      (__attribute__((address_space(3))) unsigned int*)l, 16, 0, 0);
}

// ---------------- temporal attention ----------------
__global__ void k_lhs_t(const float* x, const float* U1, float* lhst) {
  int bi = blockIdx.x;                 // (b*T+t)*F + f
  int f = bi % F; int t = (bi / F) % T; int b = bi / (F * T);
  int tid = threadIdx.x;
  float acc = 0.f;
  for (int n = tid; n < N; n += 64)
    acc += x[(((size_t)b * N + n) * F + f) * T + t] * U1[n];
  #pragma unroll
  for (int off = 32; off > 0; off >>= 1) acc += __shfl_down(acc, off);
  if (tid == 0) lhst[bi] = acc;
}

__global__ void k_lhs2(const float* lhst, const float* U2, float* lhs2) {
  __shared__ float ls[F];
  int tid = threadIdx.x;
  int id = blockIdx.x * 256 + tid;   // (b*T+t)*N + n
  int n = id % N; int bt = id / N;
  if (tid < F) ls[tid] = lhst[bt * F + tid];
  __syncthreads();
  float acc = 0.f;
  #pragma unroll
  for (int f = 0; f < F; ++f) acc += ls[f] * U2[f * N + n];
  lhs2[id] = acc;
}

__global__ void k_fx(const float* x, const float* U3, const float* W3,
                     float* rhst, float* w3x) {
  __shared__ float u3s[F], w3s[F];
  int tid = threadIdx.x;
  if (tid < F) { u3s[tid] = U3[tid]; w3s[tid] = W3[tid]; }
  __syncthreads();
  int id = blockIdx.x * 256 + tid;     // (b*N+n)*T + t
  int t = id % T; int bn = id / T;
  float au = 0.f, aw = 0.f;
  #pragma unroll
  for (int f = 0; f < F; ++f) {
    float v = x[((size_t)bn * F + f) * T + t];
    au += u3s[f] * v; aw += w3s[f] * v;
  }
  rhst[id] = au; w3x[id] = aw;
}

__global__ void k_Elog(const float* lhs2, const float* rhst, float* Elog) {
  int bi = blockIdx.x;                 // (b*T+t)*T + s
  int s = bi % T; int t = (bi / T) % T; int b = bi / (T * T);
  int tid = threadIdx.x;
  float acc = 0.f;
  for (int n = tid; n < N; n += 64)
    acc += lhs2[(b * T + t) * N + n] * rhst[(b * N + n) * T + s];
  #pragma unroll
  for (int off = 32; off > 0; off >>= 1) acc += __shfl_down(acc, off);
  if (tid == 0) Elog[bi] = acc;
}

__global__ void k_Esm(const float* Elog, float* E) {
  int b = blockIdx.x; int s = threadIdx.x;
  if (s >= T) return;
  float mx = -1e30f;
  for (int t = 0; t < T; ++t) mx = fmaxf(mx, Elog[(b * T + t) * T + s]);
  float sum = 0.f;
  for (int t = 0; t < T; ++t) sum += expf(Elog[(b * T + t) * T + s] - mx);
  float inv = 1.f / sum;
  for (int t = 0; t < T; ++t)
    E[(b * T + t) * T + s] = expf(Elog[(b * T + t) * T + s] - mx) * inv;
}

__global__ void k_EW1(const float* E, const float* W1, float* EW1) {
  int b = blockIdx.x; int t = threadIdx.x;
  if (t >= T) return;
  float acc = 0.f;
  for (int s = 0; s < T; ++s) acc += E[(b * T + t) * T + s] * W1[s];
  EW1[b * T + t] = acc;
}

// ---------------- spatial attention ----------------
__global__ void k_tmp1x(const float* x, const float* EW1, float* tmp1) {
  __shared__ float ew[T];
  int tid = threadIdx.x;
  int id = blockIdx.x * 256 + tid;       // (b*N+n)*F + f
  int b = id / (N * F);
  if (tid < T) ew[tid] = EW1[b * T + tid];
  __syncthreads();
  const float* xr = x + (size_t)id * T;
  float acc = 0.f;
  #pragma unroll
  for (int t = 0; t < T; ++t) acc += xr[t] * ew[t];
  tmp1[id] = acc;
}

__global__ void k_lhs_s(const float* tmp1, const float* W2, float* lhss) {
  int id = blockIdx.x * 256 + threadIdx.x;
  int t = id % T; int bn = id / T;
  float acc = 0.f;
  #pragma unroll
  for (int f = 0; f < F; ++f) acc += tmp1[bn * F + f] * W2[f * T + t];
  lhss[id] = acc;
}

__global__ void k_rhss(const float* w3x, const float* E, float* rhss) {
  __shared__ float Ec[T];
  int tid = threadIdx.x;
  int id = blockIdx.x * 256 + tid;       // (b*T+t)*N + m
  int m = id % N; int t = (id / N) % T; int b = id / (N * T);
  if (tid < T) Ec[tid] = E[(b * T + tid) * T + t];
  __syncthreads();
  const float* wr = w3x + ((size_t)b * N + m) * T;
  float acc = 0.f;
  #pragma unroll
  for (int tp = 0; tp < T; ++tp) acc += wr[tp] * Ec[tp];
  rhss[id] = acc;
}

__global__ void k_Slog(const float* lhss, const float* rhss, __hip_bfloat16* S) {
  __shared__ float rt[T][256];
  __shared__ float lt[16][T];
  int m0 = blockIdx.x * 256, n0 = blockIdx.y * 16, b = blockIdx.z;
  int tid = threadIdx.x;
  for (int t = 0; t < T; ++t) rt[t][tid] = rhss[((size_t)b * T + t) * N + m0 + tid];
  for (int i = tid; i < 16 * T; i += 256) {
    int n = i / T, t = i % T;
    lt[n][t] = lhss[((size_t)b * N + n0 + n) * T + t];
  }
  __syncthreads();
  #pragma unroll 4
  for (int n = 0; n < 16; ++n) {
    float acc = 0.f;
    #pragma unroll
    for (int t = 0; t < T; ++t) acc += lt[n][t] * rt[t][tid];
    S[((size_t)b * N + n0 + n) * N + m0 + tid] = __float2bfloat16(acc);
  }
}

// ---------------- column softmax stats --------------------
__global__ __launch_bounds__(256) void k_Ssum(const __hip_bfloat16* S,
                                              float* pmx, float* psm) {
  int m0 = blockIdx.x * 128; int b = blockIdx.y; int z = blockIdx.z;
  int tid = threadIdx.x;
  int lane = tid & 63, nq = tid >> 6;
  int c = m0 + lane * 2;
  float mx0 = -1e30f, sm0 = 0.f, mx1 = -1e30f, sm1 = 0.f;
  #pragma unroll 4
  for (int i = 0; i < 32; ++i) {
    int n = z * 128 + i * 4 + nq;
    unsigned u = *(const unsigned*)&S[((size_t)b * N + n) * N + c];
    float v0 = us2f((unsigned short)(u & 0xffffu));
    float v1 = us2f((unsigned short)(u >> 16));
    float nm0 = fmaxf(mx0, v0);
    sm0 = sm0 * __expf(mx0 - nm0) + __expf(v0 - nm0); mx0 = nm0;
    float nm1 = fmaxf(mx1, v1);
    sm1 = sm1 * __expf(mx1 - nm1) + __expf(v1 - nm1); mx1 = nm1;
  }
  __shared__ float lmx[4][128], lsm[4][128];
  lmx[nq][lane * 2] = mx0; lmx[nq][lane * 2 + 1] = mx1;
  lsm[nq][lane * 2] = sm0; lsm[nq][lane * 2 + 1] = sm1;
  __syncthreads();
  if (nq == 0) {
    #pragma unroll
    for (int cc2 = 0; cc2 < 2; ++cc2) {
      int col = lane * 2 + cc2;
      float M = lmx[0][col], Sg = lsm[0][col];
      #pragma unroll
      for (int s = 1; s < 4; ++s) {
        float m2 = lmx[s][col], s2 = lsm[s][col];
        float nm = fmaxf(M, m2);
        Sg = Sg * __expf(M - nm) + s2 * __expf(m2 - nm);
        M = nm;
      }
      pmx[((size_t)z * B + b) * N + m0 + col] = M;
      psm[((size_t)z * B + b) * N + m0 + col] = Sg;
    }
  }
}

// combine NSEG partials -> smax, sinv per (b,m). grid (B*N/256).
__global__ void k_Scomb(const float* pmx, const float* psm,
                        float* smax, float* sinv) {
  int id = blockIdx.x * 256 + threadIdx.x;   // b*N + m
  float M = -1e30f, Sg = 0.f;
  #pragma unroll
  for (int z = 0; z < NSEG; ++z) {
    float m2 = pmx[(size_t)z * B * N + id];
    float s2 = psm[(size_t)z * B * N + id];
    float nm = fmaxf(M, m2);
    Sg = Sg * __expf(M - nm) + s2 * __expf(m2 - nm);
    M = nm;
  }
  smax[id] = M;
  sinv[id] = 1.f / Sg;
}

// ---------------- GEMM operand prep (transpose to n-contiguous bf16) --------
__global__ __launch_bounds__(256) void k_prepA(const float* cheb,
                                               const __hip_bfloat16* S,
                                               const float* smax,
                                               const float* sinv,
                                               unsigned short* Abf,
                                               int Bc, int b0) {
  __shared__ float Tl[64][65];
  int z = blockIdx.z;
  int k = z / Bc, bl = z % Bc, b = b0 + bl;
  int n0 = blockIdx.x * 64, m0 = blockIdx.y * 64;
  int tid = threadIdx.x;
  int j = tid & 63, i4 = tid >> 6;
  float cm = smax[(size_t)b * N + m0 + j];
  float ci = sinv[(size_t)b * N + m0 + j];
  #pragma unroll
  for (int it = 0; it < 16; ++it) {
    int i = it * 4 + i4;
    Tl[i][j] = cheb[((size_t)k * N + n0 + i) * N + m0 + j] *
               (__expf(b2f(S[((size_t)b * N + n0 + i) * N + m0 + j]) - cm) * ci);
  }
  __syncthreads();
  int i2 = (tid & 31) * 2, j8 = tid >> 5;
  #pragma unroll
  for (int it = 0; it < 8; ++it) {
    int jj = it * 8 + j8;
    unsigned u = (unsigned)f2bu(Tl[i2][jj]) | ((unsigned)f2bu(Tl[i2 + 1][jj]) << 16);
    *(unsigned*)&Abf[((size_t)z * N + m0 + jj) * N + n0 + i2] = u;
  }
}

// xT[bl][c'][n] = bf16(x[b,n,f,t]) with c' = t*32+f. grid (N/64, 12, Bc)
__global__ __launch_bounds__(256) void k_prepX(const float* x, unsigned short* xT,
                                               int b0) {
  __shared__ float Tl[64][65];
  int bl = blockIdx.z, b = b0 + bl;
  int n0 = blockIdx.x * 64, c0 = blockIdx.y * 64;
  int tid = threadIdx.x;
  int j = tid & 63, i4 = tid >> 6;
  #pragma unroll
  for (int it = 0; it < 16; ++it) {
    int i = it * 4 + i4;
    Tl[i][j] = x[((size_t)b * N + n0 + i) * FT + c0 + j];
  }
  __syncthreads();
  int i2 = (tid & 31) * 2, j8 = tid >> 5;
  #pragma unroll
  for (int it = 0; it < 8; ++it) {
    int jj = it * 8 + j8;
    int c = c0 + jj;                       // old flat c = f*24+t
    int row = (c % 24) * 32 + c / 24;      // c' = t*32+f
    unsigned u = (unsigned)f2bu(Tl[i2][jj]) | ((unsigned)f2bu(Tl[i2 + 1][jj]) << 16);
    *(unsigned*)&xT[((size_t)bl * FT + row) * N + n0 + i2] = u;
  }
}

// weights -> bf16, MFMA-friendly layouts (ushort indices in wbf):
//   ThB  [o][kk=k*32+f] : [o*96 + kk]            0     .. 6143
//   tcwB [o][j*64+cc]   : [6144 + o*192 + ...]   6144  .. 18431
//   rcw pairs           : [18432 + (f>>1)*128 + o*2 + (f&1)]   .. 20479
__global__ void k_prepW(const float* Theta, const float* tcw, const float* rcw,
                        unsigned short* wbf) {
  int tid = threadIdx.x;
  for (int g = tid; g < 64 * 96; g += 256) {
    int o = g / 96, kk = g % 96;
    wbf[g] = f2bu(Theta[kk * 64 + o]);     // Theta[(k*32+f)*64 + o]
  }
  for (int g = tid; g < 64 * 192; g += 256) {
    int o = g / 192, r = g % 192;
    int jj = r / 64, cc = r % 64;
    wbf[6144 + g] = f2bu(tcw[o * 192 + cc * 3 + jj]);
  }
  for (int g = tid; g < 32 * 64; g += 256) {
    int f = g >> 6, o = g & 63;
    wbf[18432 + (f >> 1) * 128 + o * 2 + (f & 1)] = f2bu(rcw[o * 32 + f]);
  }
}

// ------- Chebyshev contraction + fused Theta epilogue (MFMA bf16 v6) --------
// Main loop as r13 (gload_lds + both-sides XOR swizzle + XCD remap). Theta
// epilogue half-split through A_th[128][104] (26624 B) so LDS stays at the
// staging footprint 40960 B -> 4 blocks/CU. Writers half h = waves wmi==h;
// readers = waves (w>>1)==h. Same values, same rounding as r12/r13.
__global__ __launch_bounds__(256, 4) void k_gemm3(const unsigned short* Abf,
                                                  const unsigned short* xT,
                                                  const unsigned short* wbf,
                                                  unsigned short* sg,
                                                  int Bc) {
  __shared__ __align__(16) unsigned char smem[40960];
  unsigned short* A_l  = (unsigned short*)smem;            // [3*64][64] staging
  unsigned short* X_l  = (unsigned short*)(smem + 24576);  // [128][64]  staging
  unsigned short* A_th = (unsigned short*)smem;            // [128][104] epilogue
  int p = blockIdx.x;
  int xcd = p & 7, slot = p >> 3;
  int g = xcd * (2 * Bc) + slot / 6;
  int cx = slot % 6;
  int bl = g >> 4, my = g & 15;
  int m0 = my * 64, c0 = cx * 128;
  int t0 = cx * 4;
  int tid = threadIdx.x;
  int lane = tid & 63, w = tid >> 6;
  int l15 = lane & 15, quad = lane >> 4;
  int wmi = w & 1, wci = w >> 1;
  int nh = lane & 7, ml = lane >> 3;
  int swz = nh ^ ml;                       // pre-swizzled source chunk

  f32x4 acc[3][2][4];
  #pragma unroll
  for (int k = 0; k < 3; ++k)
    #pragma unroll
    for (int mt = 0; mt < 2; ++mt)
      #pragma unroll
      for (int ct = 0; ct < 4; ++ct) acc[k][mt][ct] = (f32x4){0.f, 0.f, 0.f, 0.f};

  for (int n0 = 0; n0 < N; n0 += 64) {
    #pragma unroll
    for (int it = 0; it < 6; ++it) {               // A: 3k x 64m x 64n
      int k = it >> 1, mh = it & 1;
      int rowb = mh * 32 + w * 8;
      gload16(&Abf[((size_t)(k * Bc + bl) * N + m0 + rowb + ml) * N + n0 + swz * 8],
              &A_l[(k * 64 + rowb) * 64]);
    }
    #pragma unroll
    for (int it = 0; it < 4; ++it) {               // X: 128c x 64n
      int cb = it * 32 + w * 8;
      gload16(&xT[((size_t)bl * FT + c0 + cb + ml) * N + n0 + swz * 8],
              &X_l[cb * 64]);
    }
    __syncthreads();
    #pragma unroll
    for (int ks = 0; ks < 2; ++ks) {
      short8 bfr[4];
      #pragma unroll
      for (int ct = 0; ct < 4; ++ct) {
        int row = wci * 64 + ct * 16 + l15;
        int pc = (ks * 4 + quad) ^ (row & 7);
        bfr[ct] = *(const short8*)&X_l[row * 64 + pc * 8];
      }
      #pragma unroll
      for (int k = 0; k < 3; ++k)
        #pragma unroll
        for (int mt = 0; mt < 2; ++mt) {
          int row = wmi * 32 + mt * 16 + l15;
          int pc = (ks * 4 + quad) ^ (row & 7);
          short8 af = *(const short8*)&A_l[(k * 64 + row) * 64 + pc * 8];
          #pragma unroll
          for (int ct = 0; ct < 4; ++ct)
            acc[k][mt][ct] = __builtin_amdgcn_mfma_f32_16x16x32_bf16(
                af, bfr[ct], acc[k][mt][ct], 0, 0, 0);
        }
    }
    __syncthreads();
  }

  // ---- theta epilogue, half-split (rho 0..127 then 128..255) ----
  short8 bth[4][3];
  #pragma unroll
  for (int ot = 0; ot < 4; ++ot)
    #pragma unroll
    for (int ks = 0; ks < 3; ++ks)
      bth[ot][ks] = *(const short8*)&wbf[(ot * 16 + l15) * 96 + ks * 32 + quad * 8];

  #pragma unroll
  for (int h = 0; h < 2; ++h) {
    if (wmi == h) {                       // writers: acc rows mloc-h*32 = 0..31
      #pragma unroll
      for (int k = 0; k < 3; ++k)
        #pragma unroll
        for (int mt = 0; mt < 2; ++mt)
          #pragma unroll
          for (int ct = 0; ct < 4; ++ct) {
            int tl = wci * 2 + (ct >> 1);
            int f  = (ct & 1) * 16 + l15;
            #pragma unroll
            for (int r = 0; r < 4; ++r) {
              int mrel = mt * 16 + quad * 4 + r;
              A_th[(mrel * 4 + tl) * 104 + k * 32 + f] = f2bu(acc[k][mt][ct][r]);
            }
          }
    }
    __syncthreads();
    if ((w >> 1) == h) {                  // readers: tiles h*8 .. h*8+7
      int wl = w & 1;
      #pragma unroll
      for (int i = 0; i < 4; ++i) {
        int tloc = wl * 4 + i;            // 0..7 within the half
        short8 af[3];
        #pragma unroll
        for (int ks = 0; ks < 3; ++ks)
          af[ks] = *(const short8*)&A_th[(tloc * 16 + l15) * 104 + ks * 32 + quad * 8];
        int mloc = h * 32 + tloc * 4 + quad;
        size_t base = ((size_t)(bl * N + m0 + mloc)) * (T * CC) + (size_t)t0 * CC;
        #pragma unroll
        for (int ot = 0; ot < 4; ++ot) {
          f32x4 th = (f32x4){0.f, 0.f, 0.f, 0.f};
          #pragma unroll
          for (int ks = 0; ks < 3; ++ks)
            th = __builtin_amdgcn_mfma_f32_16x16x32_bf16(af[ks], bth[ot][ks], th,
                                                         0, 0, 0);
          #pragma unroll
          for (int rr = 0; rr < 4; ++rr)   // rho&3 = rr -> t = t0+rr
            sg[base + (size_t)rr * CC + ot * 16 + l15] = f2bu(fmaxf(th[rr], 0.f));
        }
      }
    }
    __syncthreads();
  }
}

// ---------------- tail: conv (MFMA) + residual + LN -------------------------
__global__ __launch_bounds__(256) void k_tail(const unsigned short* sg,
                                              const float* x,
                                              const unsigned short* wbf,
                                              const float* tcb, const float* rcb,
                                              const float* gam, const float* bet,
                                              float* out, int b0) {
  __shared__ __align__(16) unsigned char smem[38272];
  float* co_l = (float*)(smem + 13312);             // [96][65] f32
  int tid = threadIdx.x;
  int w = tid >> 6, lane = tid & 63;
  int l15 = lane & 15, quad = lane >> 4;
  int r0l = blockIdx.x * 4;
  int o0 = w * 16;

  short8 btc[6];
  {
    int o = o0 + l15;
    #pragma unroll
    for (int s = 0; s < 6; ++s)
      btc[s] = *(const short8*)&wbf[6144 + o * 192 + s * 32 + quad * 8];
  }

  // P0: zero pad rows + stage sg -> sg_l[m][t'][cc] (XOR-swz (rp&7)<<4,
  // 16B-chunk granular so uint4 copies preserve the swizzle).
  if (tid < 64) {
    int m = tid >> 4, rr = (tid >> 3) & 1, ck = tid & 7;
    int rp = m * 26 + rr * 25;
    *(uint4*)(smem + rp * 128 + ((ck * 16) ^ ((rp & 7) << 4))) =
        make_uint4(0, 0, 0, 0);
  }
  #pragma unroll
  for (int it = 0; it < 3; ++it) {       // 768 chunks of 16B
    int ch = it * 256 + tid;
    int m = ch / 192, rem = ch % 192;
    int t = rem >> 3, ck = rem & 7;
    uint4 v = *(const uint4*)&sg[((size_t)(r0l + m)) * (T * CC) + t * CC + ck * 8];
    int rp = m * 26 + t + 1;
    *(uint4*)(smem + rp * 128 + ((ck * 16) ^ ((rp & 7) << 4))) = v;
  }
  __syncthreads();

  // conv MFMA, K = 192 (j*64+cc); A row (m,t) col j*64+cc = sg[m][t+j][cc].
  f32x4 cv[6];
  #pragma unroll
  for (int Mt = 0; Mt < 6; ++Mt) {
    int row = Mt * 16 + l15;
    int m = row / 24, t = row % 24;
    cv[Mt] = (f32x4){0.f, 0.f, 0.f, 0.f};
    #pragma unroll
    for (int s = 0; s < 6; ++s) {
      int rp = m * 26 + t + (s >> 1);
      int cb = (32 * (s & 1) + quad * 8) * 2;
      short8 af = *(const short8*)(smem + rp * 128 + (cb ^ ((rp & 7) << 4)));
      cv[Mt] = __builtin_amdgcn_mfma_f32_16x16x32_bf16(af, btc[s], cv[Mt], 0, 0, 0);
    }
  }
  #pragma unroll
  for (int Mt = 0; Mt < 6; ++Mt)
    #pragma unroll
    for (int r = 0; r < 4; ++r) {
      int row = Mt * 16 + quad * 4 + r;
      co_l[row * 65 + o0 + l15] = cv[Mt][r];
    }
  __syncthreads();

  // per-lane o; bias + residual (fp32) + relu + LN + store.
  int o = lane;
  float bias = tcb[o] + rcb[o];
  float acc[T];
  #pragma unroll
  for (int t = 0; t < T; ++t) acc[t] = co_l[(w * 24 + t) * 65 + o] + bias;

  size_t grow = (size_t)b0 * N + r0l + w;
  const float* xrow = x + grow * FT;
  const unsigned* rcp = (const unsigned*)(wbf + 18432);
  #pragma unroll 4
  for (int f2 = 0; f2 < 16; ++f2) {
    unsigned u = rcp[f2 * 64 + o];
    float wf0 = us2f((unsigned short)(u & 0xffffu));
    float wf1 = us2f((unsigned short)(u >> 16));
    const float4* xp0 = (const float4*)&xrow[(f2 * 2) * 24];     // wave-uniform
    const float4* xp1 = (const float4*)&xrow[(f2 * 2 + 1) * 24]; // broadcast
    #pragma unroll
    for (int q = 0; q < 6; ++q) {
      float4 v0 = xp0[q], v1 = xp1[q];
      acc[q * 4 + 0] += wf0 * v0.x + wf1 * v1.x;
      acc[q * 4 + 1] += wf0 * v0.y + wf1 * v1.y;
      acc[q * 4 + 2] += wf0 * v0.z + wf1 * v1.z;
      acc[q * 4 + 3] += wf0 * v0.w + wf1 * v1.w;
    }
  }
  float g = gam[o], be = bet[o];
  #pragma unroll
  for (int t = 0; t < T; ++t) {
    float z = fmaxf(acc[t], 0.f);
    float s = z, q = z * z;
    #pragma unroll
    for (int off = 1; off < 64; off <<= 1) {
      s += __shfl_xor(s, off);
      q += __shfl_xor(q, off);
    }
    float mu = s * (1.f / 64.f);
    float var = q * (1.f / 64.f) - mu * mu;
    acc[t] = (z - mu) * rsqrtf(var + 1e-5f) * g + be;
  }
  float* orow = out + grow * CTT + o * T;
  #pragma unroll
  for (int q = 0; q < 6; ++q)
    ((float4*)orow)[q] =
        make_float4(acc[q * 4], acc[q * 4 + 1], acc[q * 4 + 2], acc[q * 4 + 3]);
}

}  // namespace

extern "C" void kernel_launch(void* const* d_in, const int* in_sizes, int n_in,
                              void* d_out, int out_size, void* d_ws, size_t ws_size,
                              hipStream_t stream) {
  (void)in_sizes; (void)n_in; (void)out_size;
  const float* x     = (const float*)d_in[0];
  const float* W1    = (const float*)d_in[1];
  const float* W2    = (const float*)d_in[2];
  const float* W3    = (const float*)d_in[3];
  const float* U1    = (const float*)d_in[4];
  const float* U2    = (const float*)d_in[5];
  const float* U3    = (const float*)d_in[6];
  const float* cheb  = (const float*)d_in[7];
  const float* Theta = (const float*)d_in[8];
  const float* tcw   = (const float*)d_in[9];
  const float* tcb   = (const float*)d_in[10];
  const float* rcw   = (const float*)d_in[11];
  const float* rcb   = (const float*)d_in[12];
  const float* gam   = (const float*)d_in[13];
  const float* bet   = (const float*)d_in[14];
  float* out = (float*)d_out;

  // ---- runtime-adaptive workspace layout ----
  const size_t SB_BYTES = (size_t)B * N * N * 2;          // 33,554,432 (S bf16)
  const size_t WB_BYTES = 65536;                          // wbf (40960 used)
  const size_t AB_PER_B = (size_t)3 * N * N * 2;          // 6,291,456
  const size_t XT_PER_B = (size_t)FT * N * 2;             // 1,572,864
  const size_t SG_PER_B = (size_t)N * T * CC * 2;         // 3,145,728
  const size_t SMALL = 2816384 * 4;                       // 11,265,536 B
  int Bc = 16;
  while (Bc > 1 && SB_BYTES + WB_BYTES + SMALL +
             (size_t)Bc * (AB_PER_B + XT_PER_B + SG_PER_B) > ws_size)
    Bc >>= 1;

  char* w = (char*)d_ws;
  __hip_bfloat16* Sb = (__hip_bfloat16*)w;
  unsigned short* wbf = (unsigned short*)(w + SB_BYTES);
  unsigned short* Abf = (unsigned short*)(w + SB_BYTES + WB_BYTES);
  unsigned short* xTb = (unsigned short*)(w + SB_BYTES + WB_BYTES +
                                          (size_t)Bc * AB_PER_B);
  unsigned short* sgb = (unsigned short*)(w + SB_BYTES + WB_BYTES +
                                          (size_t)Bc * (AB_PER_B + XT_PER_B));
  float* sm = (float*)(w + SB_BYTES + WB_BYTES +
                       (size_t)Bc * (AB_PER_B + XT_PER_B + SG_PER_B));
  float* lhst = sm;                       // B*T*F   = 12288
  float* lhs2 = lhst + B * T * F;         // B*T*N   = 393216
  float* rhst = lhs2 + B * T * N;         // B*N*T   = 393216
  float* w3x  = rhst + B * N * T;         // B*N*T   = 393216
  float* Elog = w3x + B * N * T;          // B*T*T   = 9216
  float* E    = Elog + B * T * T;         // B*T*T   = 9216
  float* EW1  = E + B * T * T;            // B*T     = 384
  float* tmp1 = EW1 + B * T;              // B*N*F   = 524288
  float* lhss = tmp1 + B * N * F;         // B*N*T   = 393216
  float* rhss = lhss + B * N * T;         // B*N*T   = 393216
  float* pmx  = rhss + B * N * T;         // NSEG*B*N = 131072
  float* psm  = pmx + NSEG * B * N;       // NSEG*B*N = 131072
  float* smax = psm + NSEG * B * N;       // B*N     = 16384
  float* sinv = smax + B * N;             // B*N     = 16384

  // temporal attention
  k_lhs_t<<<B * T * F, 64, 0, stream>>>(x, U1, lhst);
  k_lhs2<<<(B * T * N) / 256, 256, 0, stream>>>(lhst, U2, lhs2);
  k_fx<<<(B * N * T) / 256, 256, 0, stream>>>(x, U3, W3, rhst, w3x);
  k_Elog<<<B * T * T, 64, 0, stream>>>(lhs2, rhst, Elog);
  k_Esm<<<B, 64, 0, stream>>>(Elog, E);
  k_EW1<<<B, 64, 0, stream>>>(E, W1, EW1);

  // spatial attention (x_TAt folded out)
  k_tmp1x<<<(B * N * F) / 256, 256, 0, stream>>>(x, EW1, tmp1);
  k_lhs_s<<<(B * N * T) / 256, 256, 0, stream>>>(tmp1, W2, lhss);
  k_rhss<<<(B * N * T) / 256, 256, 0, stream>>>(w3x, E, rhss);
  k_Slog<<<dim3(N / 256, N / 16, B), 256, 0, stream>>>(lhss, rhss, Sb);
  k_Ssum<<<dim3(N / 128, B, NSEG), 256, 0, stream>>>(Sb, pmx, psm);
  k_Scomb<<<(B * N) / 256, 256, 0, stream>>>(pmx, psm, smax, sinv);

  // weight prep (once)
  k_prepW<<<1, 256, 0, stream>>>(Theta, tcw, rcw, wbf);

  // per-chunk: operand prep + fused GEMM(+theta) + tail epilogue
  for (int b0 = 0; b0 < B; b0 += Bc) {
    k_prepA<<<dim3(N / 64, N / 64, 3 * Bc), 256, 0, stream>>>(cheb, Sb, smax,
                                                              sinv, Abf, Bc, b0);
    k_prepX<<<dim3(N / 64, FT / 64, Bc), 256, 0, stream>>>(x, xTb, b0);
    k_gemm3<<<dim3(96 * Bc), 256, 0, stream>>>(Abf, xTb, wbf, sgb, Bc);
    k_tail<<<Bc * N / 4, 256, 0, stream>>>(sgb, x, wbf, tcb, rcb,
                                           gam, bet, out, b0);
  }
}

// Round 9
// 695.283 us; speedup vs baseline: 1.1994x; 1.1994x over previous
//
#include <hip/hip_runtime.h>
#include <hip/hip_bf16.h>
#include <math.h>

// ASTGCN block, MI355X. Round 15: revert r14's __launch_bounds__(256,4) on
// k_gemm3 — it collapsed VGPR 136->64 and spilled the MFMA accumulators to
// scratch (WRITE_SIZE 49->524MB, dur 176->312us). Same failure mode as r7:
// min-waves bounds overshoot downward on this compiler. Keep the half-split
// theta epilogue (LDS 40960) — harmless, and the natural 136-VGPR allocation
// is the binding resource at 3 blocks/CU.

namespace {

constexpr int B = 16, N = 1024, F = 32, T = 24, CC = 64, CT = 64;
constexpr int FT = F * T;     // 768
constexpr int CTT = CT * T;   // 1536
constexpr int NSEG = 8;       // softmax n-segments

using f32x4  = __attribute__((ext_vector_type(4))) float;
using short8 = __attribute__((ext_vector_type(8))) short;

__device__ __forceinline__ float b2f(__hip_bfloat16 v) { return __bfloat162float(v); }
__device__ __forceinline__ unsigned short f2bu(float x) {   // fp32 -> bf16 bits, RNE
  union { float f; unsigned u; } c; c.f = x;
  unsigned u = c.u;
  return (unsigned short)((u + 0x7FFFu + ((u >> 16) & 1u)) >> 16);
}
__device__ __forceinline__ float us2f(unsigned short u) {   // bf16 bits -> fp32
  union { unsigned u; float f; } c; c.u = ((unsigned)u) << 16; return c.f;
}
__device__ __forceinline__ void gload16(const void* g, void* l) {
  __builtin_amdgcn_global_load_lds(
      (const __attribute__((address_space(1))) unsigned int*)g,
      (__attribute__((address_space(3))) unsigned int*)l, 16, 0, 0);
}

// ---------------- temporal attention ----------------
__global__ void k_lhs_t(const float* x, const float* U1, float* lhst) {
  int bi = blockIdx.x;                 // (b*T+t)*F + f
  int f = bi % F; int t = (bi / F) % T; int b = bi / (F * T);
  int tid = threadIdx.x;
  float acc = 0.f;
  for (int n = tid; n < N; n += 64)
    acc += x[(((size_t)b * N + n) * F + f) * T + t] * U1[n];
  #pragma unroll
  for (int off = 32; off > 0; off >>= 1) acc += __shfl_down(acc, off);
  if (tid == 0) lhst[bi] = acc;
}

__global__ void k_lhs2(const float* lhst, const float* U2, float* lhs2) {
  __shared__ float ls[F];
  int tid = threadIdx.x;
  int id = blockIdx.x * 256 + tid;   // (b*T+t)*N + n
  int n = id % N; int bt = id / N;
  if (tid < F) ls[tid] = lhst[bt * F + tid];
  __syncthreads();
  float acc = 0.f;
  #pragma unroll
  for (int f = 0; f < F; ++f) acc += ls[f] * U2[f * N + n];
  lhs2[id] = acc;
}

__global__ void k_fx(const float* x, const float* U3, const float* W3,
                     float* rhst, float* w3x) {
  __shared__ float u3s[F], w3s[F];
  int tid = threadIdx.x;
  if (tid < F) { u3s[tid] = U3[tid]; w3s[tid] = W3[tid]; }
  __syncthreads();
  int id = blockIdx.x * 256 + tid;     // (b*N+n)*T + t
  int t = id % T; int bn = id / T;
  float au = 0.f, aw = 0.f;
  #pragma unroll
  for (int f = 0; f < F; ++f) {
    float v = x[((size_t)bn * F + f) * T + t];
    au += u3s[f] * v; aw += w3s[f] * v;
  }
  rhst[id] = au; w3x[id] = aw;
}

__global__ void k_Elog(const float* lhs2, const float* rhst, float* Elog) {
  int bi = blockIdx.x;                 // (b*T+t)*T + s
  int s = bi % T; int t = (bi / T) % T; int b = bi / (T * T);
  int tid = threadIdx.x;
  float acc = 0.f;
  for (int n = tid; n < N; n += 64)
    acc += lhs2[(b * T + t) * N + n] * rhst[(b * N + n) * T + s];
  #pragma unroll
  for (int off = 32; off > 0; off >>= 1) acc += __shfl_down(acc, off);
  if (tid == 0) Elog[bi] = acc;
}

__global__ void k_Esm(const float* Elog, float* E) {
  int b = blockIdx.x; int s = threadIdx.x;
  if (s >= T) return;
  float mx = -1e30f;
  for (int t = 0; t < T; ++t) mx = fmaxf(mx, Elog[(b * T + t) * T + s]);
  float sum = 0.f;
  for (int t = 0; t < T; ++t) sum += expf(Elog[(b * T + t) * T + s] - mx);
  float inv = 1.f / sum;
  for (int t = 0; t < T; ++t)
    E[(b * T + t) * T + s] = expf(Elog[(b * T + t) * T + s] - mx) * inv;
}

__global__ void k_EW1(const float* E, const float* W1, float* EW1) {
  int b = blockIdx.x; int t = threadIdx.x;
  if (t >= T) return;
  float acc = 0.f;
  for (int s = 0; s < T; ++s) acc += E[(b * T + t) * T + s] * W1[s];
  EW1[b * T + t] = acc;
}

// ---------------- spatial attention ----------------
__global__ void k_tmp1x(const float* x, const float* EW1, float* tmp1) {
  __shared__ float ew[T];
  int tid = threadIdx.x;
  int id = blockIdx.x * 256 + tid;       // (b*N+n)*F + f
  int b = id / (N * F);
  if (tid < T) ew[tid] = EW1[b * T + tid];
  __syncthreads();
  const float* xr = x + (size_t)id * T;
  float acc = 0.f;
  #pragma unroll
  for (int t = 0; t < T; ++t) acc += xr[t] * ew[t];
  tmp1[id] = acc;
}

__global__ void k_lhs_s(const float* tmp1, const float* W2, float* lhss) {
  int id = blockIdx.x * 256 + threadIdx.x;
  int t = id % T; int bn = id / T;
  float acc = 0.f;
  #pragma unroll
  for (int f = 0; f < F; ++f) acc += tmp1[bn * F + f] * W2[f * T + t];
  lhss[id] = acc;
}

__global__ void k_rhss(const float* w3x, const float* E, float* rhss) {
  __shared__ float Ec[T];
  int tid = threadIdx.x;
  int id = blockIdx.x * 256 + tid;       // (b*T+t)*N + m
  int m = id % N; int t = (id / N) % T; int b = id / (N * T);
  if (tid < T) Ec[tid] = E[(b * T + tid) * T + t];
  __syncthreads();
  const float* wr = w3x + ((size_t)b * N + m) * T;
  float acc = 0.f;
  #pragma unroll
  for (int tp = 0; tp < T; ++tp) acc += wr[tp] * Ec[tp];
  rhss[id] = acc;
}

__global__ void k_Slog(const float* lhss, const float* rhss, __hip_bfloat16* S) {
  __shared__ float rt[T][256];
  __shared__ float lt[16][T];
  int m0 = blockIdx.x * 256, n0 = blockIdx.y * 16, b = blockIdx.z;
  int tid = threadIdx.x;
  for (int t = 0; t < T; ++t) rt[t][tid] = rhss[((size_t)b * T + t) * N + m0 + tid];
  for (int i = tid; i < 16 * T; i += 256) {
    int n = i / T, t = i % T;
    lt[n][t] = lhss[((size_t)b * N + n0 + n) * T + t];
  }
  __syncthreads();
  #pragma unroll 4
  for (int n = 0; n < 16; ++n) {
    float acc = 0.f;
    #pragma unroll
    for (int t = 0; t < T; ++t) acc += lt[n][t] * rt[t][tid];
    S[((size_t)b * N + n0 + n) * N + m0 + tid] = __float2bfloat16(acc);
  }
}

// ---------------- column softmax stats --------------------
__global__ __launch_bounds__(256) void k_Ssum(const __hip_bfloat16* S,
                                              float* pmx, float* psm) {
  int m0 = blockIdx.x * 128; int b = blockIdx.y; int z = blockIdx.z;
  int tid = threadIdx.x;
  int lane = tid & 63, nq = tid >> 6;
  int c = m0 + lane * 2;
  float mx0 = -1e30f, sm0 = 0.f, mx1 = -1e30f, sm1 = 0.f;
  #pragma unroll 4
  for (int i = 0; i < 32; ++i) {
    int n = z * 128 + i * 4 + nq;
    unsigned u = *(const unsigned*)&S[((size_t)b * N + n) * N + c];
    float v0 = us2f((unsigned short)(u & 0xffffu));
    float v1 = us2f((unsigned short)(u >> 16));
    float nm0 = fmaxf(mx0, v0);
    sm0 = sm0 * __expf(mx0 - nm0) + __expf(v0 - nm0); mx0 = nm0;
    float nm1 = fmaxf(mx1, v1);
    sm1 = sm1 * __expf(mx1 - nm1) + __expf(v1 - nm1); mx1 = nm1;
  }
  __shared__ float lmx[4][128], lsm[4][128];
  lmx[nq][lane * 2] = mx0; lmx[nq][lane * 2 + 1] = mx1;
  lsm[nq][lane * 2] = sm0; lsm[nq][lane * 2 + 1] = sm1;
  __syncthreads();
  if (nq == 0) {
    #pragma unroll
    for (int cc2 = 0; cc2 < 2; ++cc2) {
      int col = lane * 2 + cc2;
      float M = lmx[0][col], Sg = lsm[0][col];
      #pragma unroll
      for (int s = 1; s < 4; ++s) {
        float m2 = lmx[s][col], s2 = lsm[s][col];
        float nm = fmaxf(M, m2);
        Sg = Sg * __expf(M - nm) + s2 * __expf(m2 - nm);
        M = nm;
      }
      pmx[((size_t)z * B + b) * N + m0 + col] = M;
      psm[((size_t)z * B + b) * N + m0 + col] = Sg;
    }
  }
}

// combine NSEG partials -> smax, sinv per (b,m). grid (B*N/256).
__global__ void k_Scomb(const float* pmx, const float* psm,
                        float* smax, float* sinv) {
  int id = blockIdx.x * 256 + threadIdx.x;   // b*N + m
  float M = -1e30f, Sg = 0.f;
  #pragma unroll
  for (int z = 0; z < NSEG; ++z) {
    float m2 = pmx[(size_t)z * B * N + id];
    float s2 = psm[(size_t)z * B * N + id];
    float nm = fmaxf(M, m2);
    Sg = Sg * __expf(M - nm) + s2 * __expf(m2 - nm);
    M = nm;
  }
  smax[id] = M;
  sinv[id] = 1.f / Sg;
}

// ---------------- GEMM operand prep (transpose to n-contiguous bf16) --------
__global__ __launch_bounds__(256) void k_prepA(const float* cheb,
                                               const __hip_bfloat16* S,
                                               const float* smax,
                                               const float* sinv,
                                               unsigned short* Abf,
                                               int Bc, int b0) {
  __shared__ float Tl[64][65];
  int z = blockIdx.z;
  int k = z / Bc, bl = z % Bc, b = b0 + bl;
  int n0 = blockIdx.x * 64, m0 = blockIdx.y * 64;
  int tid = threadIdx.x;
  int j = tid & 63, i4 = tid >> 6;
  float cm = smax[(size_t)b * N + m0 + j];
  float ci = sinv[(size_t)b * N + m0 + j];
  #pragma unroll
  for (int it = 0; it < 16; ++it) {
    int i = it * 4 + i4;
    Tl[i][j] = cheb[((size_t)k * N + n0 + i) * N + m0 + j] *
               (__expf(b2f(S[((size_t)b * N + n0 + i) * N + m0 + j]) - cm) * ci);
  }
  __syncthreads();
  int i2 = (tid & 31) * 2, j8 = tid >> 5;
  #pragma unroll
  for (int it = 0; it < 8; ++it) {
    int jj = it * 8 + j8;
    unsigned u = (unsigned)f2bu(Tl[i2][jj]) | ((unsigned)f2bu(Tl[i2 + 1][jj]) << 16);
    *(unsigned*)&Abf[((size_t)z * N + m0 + jj) * N + n0 + i2] = u;
  }
}

// xT[bl][c'][n] = bf16(x[b,n,f,t]) with c' = t*32+f. grid (N/64, 12, Bc)
__global__ __launch_bounds__(256) void k_prepX(const float* x, unsigned short* xT,
                                               int b0) {
  __shared__ float Tl[64][65];
  int bl = blockIdx.z, b = b0 + bl;
  int n0 = blockIdx.x * 64, c0 = blockIdx.y * 64;
  int tid = threadIdx.x;
  int j = tid & 63, i4 = tid >> 6;
  #pragma unroll
  for (int it = 0; it < 16; ++it) {
    int i = it * 4 + i4;
    Tl[i][j] = x[((size_t)b * N + n0 + i) * FT + c0 + j];
  }
  __syncthreads();
  int i2 = (tid & 31) * 2, j8 = tid >> 5;
  #pragma unroll
  for (int it = 0; it < 8; ++it) {
    int jj = it * 8 + j8;
    int c = c0 + jj;                       // old flat c = f*24+t
    int row = (c % 24) * 32 + c / 24;      // c' = t*32+f
    unsigned u = (unsigned)f2bu(Tl[i2][jj]) | ((unsigned)f2bu(Tl[i2 + 1][jj]) << 16);
    *(unsigned*)&xT[((size_t)bl * FT + row) * N + n0 + i2] = u;
  }
}

// weights -> bf16, MFMA-friendly layouts (ushort indices in wbf):
//   ThB  [o][kk=k*32+f] : [o*96 + kk]            0     .. 6143
//   tcwB [o][j*64+cc]   : [6144 + o*192 + ...]   6144  .. 18431
//   rcw pairs           : [18432 + (f>>1)*128 + o*2 + (f&1)]   .. 20479
__global__ void k_prepW(const float* Theta, const float* tcw, const float* rcw,
                        unsigned short* wbf) {
  int tid = threadIdx.x;
  for (int g = tid; g < 64 * 96; g += 256) {
    int o = g / 96, kk = g % 96;
    wbf[g] = f2bu(Theta[kk * 64 + o]);     // Theta[(k*32+f)*64 + o]
  }
  for (int g = tid; g < 64 * 192; g += 256) {
    int o = g / 192, r = g % 192;
    int jj = r / 64, cc = r % 64;
    wbf[6144 + g] = f2bu(tcw[o * 192 + cc * 3 + jj]);
  }
  for (int g = tid; g < 32 * 64; g += 256) {
    int f = g >> 6, o = g & 63;
    wbf[18432 + (f >> 1) * 128 + o * 2 + (f & 1)] = f2bu(rcw[o * 32 + f]);
  }
}

// ------- Chebyshev contraction + fused Theta epilogue (MFMA bf16 v7) --------
// Main loop as r13 (gload_lds + both-sides XOR swizzle + XCD remap). Theta
// epilogue half-split through A_th[128][104] (LDS total 40960). Plain launch
// bounds: natural VGPR (~136) is the operating point — forcing min-waves
// spills (r14: VGPR 64, 524MB scratch writes).
__global__ __launch_bounds__(256) void k_gemm3(const unsigned short* Abf,
                                               const unsigned short* xT,
                                               const unsigned short* wbf,
                                               unsigned short* sg,
                                               int Bc) {
  __shared__ __align__(16) unsigned char smem[40960];
  unsigned short* A_l  = (unsigned short*)smem;            // [3*64][64] staging
  unsigned short* X_l  = (unsigned short*)(smem + 24576);  // [128][64]  staging
  unsigned short* A_th = (unsigned short*)smem;            // [128][104] epilogue
  int p = blockIdx.x;
  int xcd = p & 7, slot = p >> 3;
  int g = xcd * (2 * Bc) + slot / 6;
  int cx = slot % 6;
  int bl = g >> 4, my = g & 15;
  int m0 = my * 64, c0 = cx * 128;
  int t0 = cx * 4;
  int tid = threadIdx.x;
  int lane = tid & 63, w = tid >> 6;
  int l15 = lane & 15, quad = lane >> 4;
  int wmi = w & 1, wci = w >> 1;
  int nh = lane & 7, ml = lane >> 3;
  int swz = nh ^ ml;                       // pre-swizzled source chunk

  f32x4 acc[3][2][4];
  #pragma unroll
  for (int k = 0; k < 3; ++k)
    #pragma unroll
    for (int mt = 0; mt < 2; ++mt)
      #pragma unroll
      for (int ct = 0; ct < 4; ++ct) acc[k][mt][ct] = (f32x4){0.f, 0.f, 0.f, 0.f};

  for (int n0 = 0; n0 < N; n0 += 64) {
    #pragma unroll
    for (int it = 0; it < 6; ++it) {               // A: 3k x 64m x 64n
      int k = it >> 1, mh = it & 1;
      int rowb = mh * 32 + w * 8;
      gload16(&Abf[((size_t)(k * Bc + bl) * N + m0 + rowb + ml) * N + n0 + swz * 8],
              &A_l[(k * 64 + rowb) * 64]);
    }
    #pragma unroll
    for (int it = 0; it < 4; ++it) {               // X: 128c x 64n
      int cb = it * 32 + w * 8;
      gload16(&xT[((size_t)bl * FT + c0 + cb + ml) * N + n0 + swz * 8],
              &X_l[cb * 64]);
    }
    __syncthreads();
    #pragma unroll
    for (int ks = 0; ks < 2; ++ks) {
      short8 bfr[4];
      #pragma unroll
      for (int ct = 0; ct < 4; ++ct) {
        int row = wci * 64 + ct * 16 + l15;
        int pc = (ks * 4 + quad) ^ (row & 7);
        bfr[ct] = *(const short8*)&X_l[row * 64 + pc * 8];
      }
      #pragma unroll
      for (int k = 0; k < 3; ++k)
        #pragma unroll
        for (int mt = 0; mt < 2; ++mt) {
          int row = wmi * 32 + mt * 16 + l15;
          int pc = (ks * 4 + quad) ^ (row & 7);
          short8 af = *(const short8*)&A_l[(k * 64 + row) * 64 + pc * 8];
          #pragma unroll
          for (int ct = 0; ct < 4; ++ct)
            acc[k][mt][ct] = __builtin_amdgcn_mfma_f32_16x16x32_bf16(
                af, bfr[ct], acc[k][mt][ct], 0, 0, 0);
        }
    }
    __syncthreads();
  }

  // ---- theta epilogue, half-split (rho 0..127 then 128..255) ----
  short8 bth[4][3];
  #pragma unroll
  for (int ot = 0; ot < 4; ++ot)
    #pragma unroll
    for (int ks = 0; ks < 3; ++ks)
      bth[ot][ks] = *(const short8*)&wbf[(ot * 16 + l15) * 96 + ks * 32 + quad * 8];

  #pragma unroll
  for (int h = 0; h < 2; ++h) {
    if (wmi == h) {                       // writers: acc rows mloc-h*32 = 0..31
      #pragma unroll
      for (int k = 0; k < 3; ++k)
        #pragma unroll
        for (int mt = 0; mt < 2; ++mt)
          #pragma unroll
          for (int ct = 0; ct < 4; ++ct) {
            int tl = wci * 2 + (ct >> 1);
            int f  = (ct & 1) * 16 + l15;
            #pragma unroll
            for (int r = 0; r < 4; ++r) {
              int mrel = mt * 16 + quad * 4 + r;
              A_th[(mrel * 4 + tl) * 104 + k * 32 + f] = f2bu(acc[k][mt][ct][r]);
            }
          }
    }
    __syncthreads();
    if ((w >> 1) == h) {                  // readers: tiles h*8 .. h*8+7
      int wl = w & 1;
      #pragma unroll
      for (int i = 0; i < 4; ++i) {
        int tloc = wl * 4 + i;            // 0..7 within the half
        short8 af[3];
        #pragma unroll
        for (int ks = 0; ks < 3; ++ks)
          af[ks] = *(const short8*)&A_th[(tloc * 16 + l15) * 104 + ks * 32 + quad * 8];
        int mloc = h * 32 + tloc * 4 + quad;
        size_t base = ((size_t)(bl * N + m0 + mloc)) * (T * CC) + (size_t)t0 * CC;
        #pragma unroll
        for (int ot = 0; ot < 4; ++ot) {
          f32x4 th = (f32x4){0.f, 0.f, 0.f, 0.f};
          #pragma unroll
          for (int ks = 0; ks < 3; ++ks)
            th = __builtin_amdgcn_mfma_f32_16x16x32_bf16(af[ks], bth[ot][ks], th,
                                                         0, 0, 0);
          #pragma unroll
          for (int rr = 0; rr < 4; ++rr)   // rho&3 = rr -> t = t0+rr
            sg[base + (size_t)rr * CC + ot * 16 + l15] = f2bu(fmaxf(th[rr], 0.f));
        }
      }
    }
    __syncthreads();
  }
}

// ---------------- tail: conv (MFMA) + residual + LN -------------------------
__global__ __launch_bounds__(256) void k_tail(const unsigned short* sg,
                                              const float* x,
                                              const unsigned short* wbf,
                                              const float* tcb, const float* rcb,
                                              const float* gam, const float* bet,
                                              float* out, int b0) {
  __shared__ __align__(16) unsigned char smem[38272];
  float* co_l = (float*)(smem + 13312);             // [96][65] f32
  int tid = threadIdx.x;
  int w = tid >> 6, lane = tid & 63;
  int l15 = lane & 15, quad = lane >> 4;
  int r0l = blockIdx.x * 4;
  int o0 = w * 16;

  short8 btc[6];
  {
    int o = o0 + l15;
    #pragma unroll
    for (int s = 0; s < 6; ++s)
      btc[s] = *(const short8*)&wbf[6144 + o * 192 + s * 32 + quad * 8];
  }

  // P0: zero pad rows + stage sg -> sg_l[m][t'][cc] (XOR-swz (rp&7)<<4,
  // 16B-chunk granular so uint4 copies preserve the swizzle).
  if (tid < 64) {
    int m = tid >> 4, rr = (tid >> 3) & 1, ck = tid & 7;
    int rp = m * 26 + rr * 25;
    *(uint4*)(smem + rp * 128 + ((ck * 16) ^ ((rp & 7) << 4))) =
        make_uint4(0, 0, 0, 0);
  }
  #pragma unroll
  for (int it = 0; it < 3; ++it) {       // 768 chunks of 16B
    int ch = it * 256 + tid;
    int m = ch / 192, rem = ch % 192;
    int t = rem >> 3, ck = rem & 7;
    uint4 v = *(const uint4*)&sg[((size_t)(r0l + m)) * (T * CC) + t * CC + ck * 8];
    int rp = m * 26 + t + 1;
    *(uint4*)(smem + rp * 128 + ((ck * 16) ^ ((rp & 7) << 4))) = v;
  }
  __syncthreads();

  // conv MFMA, K = 192 (j*64+cc); A row (m,t) col j*64+cc = sg[m][t+j][cc].
  f32x4 cv[6];
  #pragma unroll
  for (int Mt = 0; Mt < 6; ++Mt) {
    int row = Mt * 16 + l15;
    int m = row / 24, t = row % 24;
    cv[Mt] = (f32x4){0.f, 0.f, 0.f, 0.f};
    #pragma unroll
    for (int s = 0; s < 6; ++s) {
      int rp = m * 26 + t + (s >> 1);
      int cb = (32 * (s & 1) + quad * 8) * 2;
      short8 af = *(const short8*)(smem + rp * 128 + (cb ^ ((rp & 7) << 4)));
      cv[Mt] = __builtin_amdgcn_mfma_f32_16x16x32_bf16(af, btc[s], cv[Mt], 0, 0, 0);
    }
  }
  #pragma unroll
  for (int Mt = 0; Mt < 6; ++Mt)
    #pragma unroll
    for (int r = 0; r < 4; ++r) {
      int row = Mt * 16 + quad * 4 + r;
      co_l[row * 65 + o0 + l15] = cv[Mt][r];
    }
  __syncthreads();

  // per-lane o; bias + residual (fp32) + relu + LN + store.
  int o = lane;
  float bias = tcb[o] + rcb[o];
  float acc[T];
  #pragma unroll
  for (int t = 0; t < T; ++t) acc[t] = co_l[(w * 24 + t) * 65 + o] + bias;

  size_t grow = (size_t)b0 * N + r0l + w;
  const float* xrow = x + grow * FT;
  const unsigned* rcp = (const unsigned*)(wbf + 18432);
  #pragma unroll 4
  for (int f2 = 0; f2 < 16; ++f2) {
    unsigned u = rcp[f2 * 64 + o];
    float wf0 = us2f((unsigned short)(u & 0xffffu));
    float wf1 = us2f((unsigned short)(u >> 16));
    const float4* xp0 = (const float4*)&xrow[(f2 * 2) * 24];     // wave-uniform
    const float4* xp1 = (const float4*)&xrow[(f2 * 2 + 1) * 24]; // broadcast
    #pragma unroll
    for (int q = 0; q < 6; ++q) {
      float4 v0 = xp0[q], v1 = xp1[q];
      acc[q * 4 + 0] += wf0 * v0.x + wf1 * v1.x;
      acc[q * 4 + 1] += wf0 * v0.y + wf1 * v1.y;
      acc[q * 4 + 2] += wf0 * v0.z + wf1 * v1.z;
      acc[q * 4 + 3] += wf0 * v0.w + wf1 * v1.w;
    }
  }
  float g = gam[o], be = bet[o];
  #pragma unroll
  for (int t = 0; t < T; ++t) {
    float z = fmaxf(acc[t], 0.f);
    float s = z, q = z * z;
    #pragma unroll
    for (int off = 1; off < 64; off <<= 1) {
      s += __shfl_xor(s, off);
      q += __shfl_xor(q, off);
    }
    float mu = s * (1.f / 64.f);
    float var = q * (1.f / 64.f) - mu * mu;
    acc[t] = (z - mu) * rsqrtf(var + 1e-5f) * g + be;
  }
  float* orow = out + grow * CTT + o * T;
  #pragma unroll
  for (int q = 0; q < 6; ++q)
    ((float4*)orow)[q] =
        make_float4(acc[q * 4], acc[q * 4 + 1], acc[q * 4 + 2], acc[q * 4 + 3]);
}

}  // namespace

extern "C" void kernel_launch(void* const* d_in, const int* in_sizes, int n_in,
                              void* d_out, int out_size, void* d_ws, size_t ws_size,
                              hipStream_t stream) {
  (void)in_sizes; (void)n_in; (void)out_size;
  const float* x     = (const float*)d_in[0];
  const float* W1    = (const float*)d_in[1];
  const float* W2    = (const float*)d_in[2];
  const float* W3    = (const float*)d_in[3];
  const float* U1    = (const float*)d_in[4];
  const float* U2    = (const float*)d_in[5];
  const float* U3    = (const float*)d_in[6];
  const float* cheb  = (const float*)d_in[7];
  const float* Theta = (const float*)d_in[8];
  const float* tcw   = (const float*)d_in[9];
  const float* tcb   = (const float*)d_in[10];
  const float* rcw   = (const float*)d_in[11];
  const float* rcb   = (const float*)d_in[12];
  const float* gam   = (const float*)d_in[13];
  const float* bet   = (const float*)d_in[14];
  float* out = (float*)d_out;

  // ---- runtime-adaptive workspace layout ----
  const size_t SB_BYTES = (size_t)B * N * N * 2;          // 33,554,432 (S bf16)
  const size_t WB_BYTES = 65536;                          // wbf (40960 used)
  const size_t AB_PER_B = (size_t)3 * N * N * 2;          // 6,291,456
  const size_t XT_PER_B = (size_t)FT * N * 2;             // 1,572,864
  const size_t SG_PER_B = (size_t)N * T * CC * 2;         // 3,145,728
  const size_t SMALL = 2816384 * 4;                       // 11,265,536 B
  int Bc = 16;
  while (Bc > 1 && SB_BYTES + WB_BYTES + SMALL +
             (size_t)Bc * (AB_PER_B + XT_PER_B + SG_PER_B) > ws_size)
    Bc >>= 1;

  char* w = (char*)d_ws;
  __hip_bfloat16* Sb = (__hip_bfloat16*)w;
  unsigned short* wbf = (unsigned short*)(w + SB_BYTES);
  unsigned short* Abf = (unsigned short*)(w + SB_BYTES + WB_BYTES);
  unsigned short* xTb = (unsigned short*)(w + SB_BYTES + WB_BYTES +
                                          (size_t)Bc * AB_PER_B);
  unsigned short* sgb = (unsigned short*)(w + SB_BYTES + WB_BYTES +
                                          (size_t)Bc * (AB_PER_B + XT_PER_B));
  float* sm = (float*)(w + SB_BYTES + WB_BYTES +
                       (size_t)Bc * (AB_PER_B + XT_PER_B + SG_PER_B));
  float* lhst = sm;                       // B*T*F   = 12288
  float* lhs2 = lhst + B * T * F;         // B*T*N   = 393216
  float* rhst = lhs2 + B * T * N;         // B*N*T   = 393216
  float* w3x  = rhst + B * N * T;         // B*N*T   = 393216
  float* Elog = w3x + B * N * T;          // B*T*T   = 9216
  float* E    = Elog + B * T * T;         // B*T*T   = 9216
  float* EW1  = E + B * T * T;            // B*T     = 384
  float* tmp1 = EW1 + B * T;              // B*N*F   = 524288
  float* lhss = tmp1 + B * N * F;         // B*N*T   = 393216
  float* rhss = lhss + B * N * T;         // B*N*T   = 393216
  float* pmx  = rhss + B * N * T;         // NSEG*B*N = 131072
  float* psm  = pmx + NSEG * B * N;       // NSEG*B*N = 131072
  float* smax = psm + NSEG * B * N;       // B*N     = 16384
  float* sinv = smax + B * N;             // B*N     = 16384

  // temporal attention
  k_lhs_t<<<B * T * F, 64, 0, stream>>>(x, U1, lhst);
  k_lhs2<<<(B * T * N) / 256, 256, 0, stream>>>(lhst, U2, lhs2);
  k_fx<<<(B * N * T) / 256, 256, 0, stream>>>(x, U3, W3, rhst, w3x);
  k_Elog<<<B * T * T, 64, 0, stream>>>(lhs2, rhst, Elog);
  k_Esm<<<B, 64, 0, stream>>>(Elog, E);
  k_EW1<<<B, 64, 0, stream>>>(E, W1, EW1);

  // spatial attention (x_TAt folded out)
  k_tmp1x<<<(B * N * F) / 256, 256, 0, stream>>>(x, EW1, tmp1);
  k_lhs_s<<<(B * N * T) / 256, 256, 0, stream>>>(tmp1, W2, lhss);
  k_rhss<<<(B * N * T) / 256, 256, 0, stream>>>(w3x, E, rhss);
  k_Slog<<<dim3(N / 256, N / 16, B), 256, 0, stream>>>(lhss, rhss, Sb);
  k_Ssum<<<dim3(N / 128, B, NSEG), 256, 0, stream>>>(Sb, pmx, psm);
  k_Scomb<<<(B * N) / 256, 256, 0, stream>>>(pmx, psm, smax, sinv);

  // weight prep (once)
  k_prepW<<<1, 256, 0, stream>>>(Theta, tcw, rcw, wbf);

  // per-chunk: operand prep + fused GEMM(+theta) + tail epilogue
  for (int b0 = 0; b0 < B; b0 += Bc) {
    k_prepA<<<dim3(N / 64, N / 64, 3 * Bc), 256, 0, stream>>>(cheb, Sb, smax,
                                                              sinv, Abf, Bc, b0);
    k_prepX<<<dim3(N / 64, FT / 64, Bc), 256, 0, stream>>>(x, xTb, b0);
    k_gemm3<<<dim3(96 * Bc), 256, 0, stream>>>(Abf, xTb, wbf, sgb, Bc);
    k_tail<<<Bc * N / 4, 256, 0, stream>>>(sgb, x, wbf, tcb, rcb,
                                           gam, bet, out, b0);
  }
}

// Round 10
// 667.499 us; speedup vs baseline: 1.2494x; 1.0416x over previous
//
#include <hip/hip_runtime.h>
#include <hip/hip_bf16.h>
#include <math.h>

// ASTGCN block, MI355X. Round 16: k_gemm3 2-phase double-buffered staging
// (T3 minimum form): BK=32, two A/X LDS buffer pairs; per phase STAGE(next)
// -> COMPUTE(cur) -> barrier, so the pre-barrier vmcnt drain only waits for
// loads that had a full compute phase in flight. Epilogue = r13's full
// A_th[256][104] (VGPR 136 operating point; r15's half-split drove VGPR to
// 184). Swizzle key (r^(r>>2))&3 on both global-source chunk and read chunk.
// Accumulation order unchanged -> bit-identical numerics. k_Esm+k_EW1 fused.

namespace {

constexpr int B = 16, N = 1024, F = 32, T = 24, CC = 64, CT = 64;
constexpr int FT = F * T;     // 768
constexpr int CTT = CT * T;   // 1536
constexpr int NSEG = 8;       // softmax n-segments

using f32x4  = __attribute__((ext_vector_type(4))) float;
using short8 = __attribute__((ext_vector_type(8))) short;

__device__ __forceinline__ float b2f(__hip_bfloat16 v) { return __bfloat162float(v); }
__device__ __forceinline__ unsigned short f2bu(float x) {   // fp32 -> bf16 bits, RNE
  union { float f; unsigned u; } c; c.f = x;
  unsigned u = c.u;
  return (unsigned short)((u + 0x7FFFu + ((u >> 16) & 1u)) >> 16);
}
__device__ __forceinline__ float us2f(unsigned short u) {   // bf16 bits -> fp32
  union { unsigned u; float f; } c; c.u = ((unsigned)u) << 16; return c.f;
}
__device__ __forceinline__ void gload16(const void* g, void* l) {
  __builtin_amdgcn_global_load_lds(
      (const __attribute__((address_space(1))) unsigned int*)g,
      (__attribute__((address_space(3))) unsigned int*)l, 16, 0, 0);
}

// ---------------- temporal attention ----------------
__global__ void k_lhs_t(const float* x, const float* U1, float* lhst) {
  int bi = blockIdx.x;                 // (b*T+t)*F + f
  int f = bi % F; int t = (bi / F) % T; int b = bi / (F * T);
  int tid = threadIdx.x;
  float acc = 0.f;
  for (int n = tid; n < N; n += 64)
    acc += x[(((size_t)b * N + n) * F + f) * T + t] * U1[n];
  #pragma unroll
  for (int off = 32; off > 0; off >>= 1) acc += __shfl_down(acc, off);
  if (tid == 0) lhst[bi] = acc;
}

__global__ void k_lhs2(const float* lhst, const float* U2, float* lhs2) {
  __shared__ float ls[F];
  int tid = threadIdx.x;
  int id = blockIdx.x * 256 + tid;   // (b*T+t)*N + n
  int n = id % N; int bt = id / N;
  if (tid < F) ls[tid] = lhst[bt * F + tid];
  __syncthreads();
  float acc = 0.f;
  #pragma unroll
  for (int f = 0; f < F; ++f) acc += ls[f] * U2[f * N + n];
  lhs2[id] = acc;
}

__global__ void k_fx(const float* x, const float* U3, const float* W3,
                     float* rhst, float* w3x) {
  __shared__ float u3s[F], w3s[F];
  int tid = threadIdx.x;
  if (tid < F) { u3s[tid] = U3[tid]; w3s[tid] = W3[tid]; }
  __syncthreads();
  int id = blockIdx.x * 256 + tid;     // (b*N+n)*T + t
  int t = id % T; int bn = id / T;
  float au = 0.f, aw = 0.f;
  #pragma unroll
  for (int f = 0; f < F; ++f) {
    float v = x[((size_t)bn * F + f) * T + t];
    au += u3s[f] * v; aw += w3s[f] * v;
  }
  rhst[id] = au; w3x[id] = aw;
}

__global__ void k_Elog(const float* lhs2, const float* rhst, float* Elog) {
  int bi = blockIdx.x;                 // (b*T+t)*T + s
  int s = bi % T; int t = (bi / T) % T; int b = bi / (T * T);
  int tid = threadIdx.x;
  float acc = 0.f;
  for (int n = tid; n < N; n += 64)
    acc += lhs2[(b * T + t) * N + n] * rhst[(b * N + n) * T + s];
  #pragma unroll
  for (int off = 32; off > 0; off >>= 1) acc += __shfl_down(acc, off);
  if (tid == 0) Elog[bi] = acc;
}

// fused: column softmax of Elog (over t) -> E, then EW1[t] = sum_s E[t,s]W1[s]
__global__ void k_EsmW1(const float* Elog, const float* W1,
                        float* E, float* EW1) {
  __shared__ float El[T][T + 1];
  int b = blockIdx.x; int s = threadIdx.x;
  if (s < T) {
    float mx = -1e30f;
    for (int t = 0; t < T; ++t) mx = fmaxf(mx, Elog[(b * T + t) * T + s]);
    float sum = 0.f;
    for (int t = 0; t < T; ++t) sum += expf(Elog[(b * T + t) * T + s] - mx);
    float inv = 1.f / sum;
    for (int t = 0; t < T; ++t) {
      float e = expf(Elog[(b * T + t) * T + s] - mx) * inv;
      E[(b * T + t) * T + s] = e;
      El[t][s] = e;
    }
  }
  __syncthreads();
  int t = threadIdx.x;
  if (t < T) {
    float acc = 0.f;
    for (int s2 = 0; s2 < T; ++s2) acc += El[t][s2] * W1[s2];
    EW1[b * T + t] = acc;
  }
}

// ---------------- spatial attention ----------------
__global__ void k_tmp1x(const float* x, const float* EW1, float* tmp1) {
  __shared__ float ew[T];
  int tid = threadIdx.x;
  int id = blockIdx.x * 256 + tid;       // (b*N+n)*F + f
  int b = id / (N * F);
  if (tid < T) ew[tid] = EW1[b * T + tid];
  __syncthreads();
  const float* xr = x + (size_t)id * T;
  float acc = 0.f;
  #pragma unroll
  for (int t = 0; t < T; ++t) acc += xr[t] * ew[t];
  tmp1[id] = acc;
}

__global__ void k_lhs_s(const float* tmp1, const float* W2, float* lhss) {
  int id = blockIdx.x * 256 + threadIdx.x;
  int t = id % T; int bn = id / T;
  float acc = 0.f;
  #pragma unroll
  for (int f = 0; f < F; ++f) acc += tmp1[bn * F + f] * W2[f * T + t];
  lhss[id] = acc;
}

__global__ void k_rhss(const float* w3x, const float* E, float* rhss) {
  __shared__ float Ec[T];
  int tid = threadIdx.x;
  int id = blockIdx.x * 256 + tid;       // (b*T+t)*N + m
  int m = id % N; int t = (id / N) % T; int b = id / (N * T);
  if (tid < T) Ec[tid] = E[(b * T + tid) * T + t];
  __syncthreads();
  const float* wr = w3x + ((size_t)b * N + m) * T;
  float acc = 0.f;
  #pragma unroll
  for (int tp = 0; tp < T; ++tp) acc += wr[tp] * Ec[tp];
  rhss[id] = acc;
}

__global__ void k_Slog(const float* lhss, const float* rhss, __hip_bfloat16* S) {
  __shared__ float rt[T][256];
  __shared__ float lt[16][T];
  int m0 = blockIdx.x * 256, n0 = blockIdx.y * 16, b = blockIdx.z;
  int tid = threadIdx.x;
  for (int t = 0; t < T; ++t) rt[t][tid] = rhss[((size_t)b * T + t) * N + m0 + tid];
  for (int i = tid; i < 16 * T; i += 256) {
    int n = i / T, t = i % T;
    lt[n][t] = lhss[((size_t)b * N + n0 + n) * T + t];
  }
  __syncthreads();
  #pragma unroll 4
  for (int n = 0; n < 16; ++n) {
    float acc = 0.f;
    #pragma unroll
    for (int t = 0; t < T; ++t) acc += lt[n][t] * rt[t][tid];
    S[((size_t)b * N + n0 + n) * N + m0 + tid] = __float2bfloat16(acc);
  }
}

// ---------------- column softmax stats --------------------
__global__ __launch_bounds__(256) void k_Ssum(const __hip_bfloat16* S,
                                              float* pmx, float* psm) {
  int m0 = blockIdx.x * 128; int b = blockIdx.y; int z = blockIdx.z;
  int tid = threadIdx.x;
  int lane = tid & 63, nq = tid >> 6;
  int c = m0 + lane * 2;
  float mx0 = -1e30f, sm0 = 0.f, mx1 = -1e30f, sm1 = 0.f;
  #pragma unroll 4
  for (int i = 0; i < 32; ++i) {
    int n = z * 128 + i * 4 + nq;
    unsigned u = *(const unsigned*)&S[((size_t)b * N + n) * N + c];
    float v0 = us2f((unsigned short)(u & 0xffffu));
    float v1 = us2f((unsigned short)(u >> 16));
    float nm0 = fmaxf(mx0, v0);
    sm0 = sm0 * __expf(mx0 - nm0) + __expf(v0 - nm0); mx0 = nm0;
    float nm1 = fmaxf(mx1, v1);
    sm1 = sm1 * __expf(mx1 - nm1) + __expf(v1 - nm1); mx1 = nm1;
  }
  __shared__ float lmx[4][128], lsm[4][128];
  lmx[nq][lane * 2] = mx0; lmx[nq][lane * 2 + 1] = mx1;
  lsm[nq][lane * 2] = sm0; lsm[nq][lane * 2 + 1] = sm1;
  __syncthreads();
  if (nq == 0) {
    #pragma unroll
    for (int cc2 = 0; cc2 < 2; ++cc2) {
      int col = lane * 2 + cc2;
      float M = lmx[0][col], Sg = lsm[0][col];
      #pragma unroll
      for (int s = 1; s < 4; ++s) {
        float m2 = lmx[s][col], s2 = lsm[s][col];
        float nm = fmaxf(M, m2);
        Sg = Sg * __expf(M - nm) + s2 * __expf(m2 - nm);
        M = nm;
      }
      pmx[((size_t)z * B + b) * N + m0 + col] = M;
      psm[((size_t)z * B + b) * N + m0 + col] = Sg;
    }
  }
}

// combine NSEG partials -> smax, sinv per (b,m). grid (B*N/256).
__global__ void k_Scomb(const float* pmx, const float* psm,
                        float* smax, float* sinv) {
  int id = blockIdx.x * 256 + threadIdx.x;   // b*N + m
  float M = -1e30f, Sg = 0.f;
  #pragma unroll
  for (int z = 0; z < NSEG; ++z) {
    float m2 = pmx[(size_t)z * B * N + id];
    float s2 = psm[(size_t)z * B * N + id];
    float nm = fmaxf(M, m2);
    Sg = Sg * __expf(M - nm) + s2 * __expf(m2 - nm);
    M = nm;
  }
  smax[id] = M;
  sinv[id] = 1.f / Sg;
}

// ---------------- GEMM operand prep (transpose to n-contiguous bf16) --------
__global__ __launch_bounds__(256) void k_prepA(const float* cheb,
                                               const __hip_bfloat16* S,
                                               const float* smax,
                                               const float* sinv,
                                               unsigned short* Abf,
                                               int Bc, int b0) {
  __shared__ float Tl[64][65];
  int z = blockIdx.z;
  int k = z / Bc, bl = z % Bc, b = b0 + bl;
  int n0 = blockIdx.x * 64, m0 = blockIdx.y * 64;
  int tid = threadIdx.x;
  int j = tid & 63, i4 = tid >> 6;
  float cm = smax[(size_t)b * N + m0 + j];
  float ci = sinv[(size_t)b * N + m0 + j];
  #pragma unroll
  for (int it = 0; it < 16; ++it) {
    int i = it * 4 + i4;
    Tl[i][j] = cheb[((size_t)k * N + n0 + i) * N + m0 + j] *
               (__expf(b2f(S[((size_t)b * N + n0 + i) * N + m0 + j]) - cm) * ci);
  }
  __syncthreads();
  int i2 = (tid & 31) * 2, j8 = tid >> 5;
  #pragma unroll
  for (int it = 0; it < 8; ++it) {
    int jj = it * 8 + j8;
    unsigned u = (unsigned)f2bu(Tl[i2][jj]) | ((unsigned)f2bu(Tl[i2 + 1][jj]) << 16);
    *(unsigned*)&Abf[((size_t)z * N + m0 + jj) * N + n0 + i2] = u;
  }
}

// xT[bl][c'][n] = bf16(x[b,n,f,t]) with c' = t*32+f. grid (N/64, 12, Bc)
__global__ __launch_bounds__(256) void k_prepX(const float* x, unsigned short* xT,
                                               int b0) {
  __shared__ float Tl[64][65];
  int bl = blockIdx.z, b = b0 + bl;
  int n0 = blockIdx.x * 64, c0 = blockIdx.y * 64;
  int tid = threadIdx.x;
  int j = tid & 63, i4 = tid >> 6;
  #pragma unroll
  for (int it = 0; it < 16; ++it) {
    int i = it * 4 + i4;
    Tl[i][j] = x[((size_t)b * N + n0 + i) * FT + c0 + j];
  }
  __syncthreads();
  int i2 = (tid & 31) * 2, j8 = tid >> 5;
  #pragma unroll
  for (int it = 0; it < 8; ++it) {
    int jj = it * 8 + j8;
    int c = c0 + jj;                       // old flat c = f*24+t
    int row = (c % 24) * 32 + c / 24;      // c' = t*32+f
    unsigned u = (unsigned)f2bu(Tl[i2][jj]) | ((unsigned)f2bu(Tl[i2 + 1][jj]) << 16);
    *(unsigned*)&xT[((size_t)bl * FT + row) * N + n0 + i2] = u;
  }
}

// weights -> bf16, MFMA-friendly layouts (ushort indices in wbf):
//   ThB  [o][kk=k*32+f] : [o*96 + kk]            0     .. 6143
//   tcwB [o][j*64+cc]   : [6144 + o*192 + ...]   6144  .. 18431
//   rcw pairs           : [18432 + (f>>1)*128 + o*2 + (f&1)]   .. 20479
__global__ void k_prepW(const float* Theta, const float* tcw, const float* rcw,
                        unsigned short* wbf) {
  int tid = threadIdx.x;
  for (int g = tid; g < 64 * 96; g += 256) {
    int o = g / 96, kk = g % 96;
    wbf[g] = f2bu(Theta[kk * 64 + o]);     // Theta[(k*32+f)*64 + o]
  }
  for (int g = tid; g < 64 * 192; g += 256) {
    int o = g / 192, r = g % 192;
    int jj = r / 64, cc = r % 64;
    wbf[6144 + g] = f2bu(tcw[o * 192 + cc * 3 + jj]);
  }
  for (int g = tid; g < 32 * 64; g += 256) {
    int f = g >> 6, o = g & 63;
    wbf[18432 + (f >> 1) * 128 + o * 2 + (f & 1)] = f2bu(rcw[o * 32 + f]);
  }
}

// ------- Chebyshev contraction + fused Theta epilogue (MFMA bf16 v8) --------
// 2-phase double-buffered staging, BK=32: STAGE(next) -> COMPUTE(cur) ->
// barrier. Buffers: A 12288B + X 8192B each, 2 pairs = 40960B; epilogue
// A_th[256][104] (full, r13 form) unions to 53248B. Swizzle key
// (r ^ (r>>2)) & 3 on global-source chunk AND read chunk. XCD remap as r13.
__global__ __launch_bounds__(256) void k_gemm3(const unsigned short* Abf,
                                               const unsigned short* xT,
                                               const unsigned short* wbf,
                                               unsigned short* sg,
                                               int Bc) {
  __shared__ __align__(16) unsigned char smem[53248];
  unsigned short* A0 = (unsigned short*)smem;             // [192][32]
  unsigned short* X0 = (unsigned short*)(smem + 12288);   // [128][32]
  unsigned short* A1 = (unsigned short*)(smem + 20480);
  unsigned short* X1 = (unsigned short*)(smem + 32768);
  unsigned short* A_th = (unsigned short*)smem;           // [256][104] epilogue
  int p = blockIdx.x;
  int xcd = p & 7, slot = p >> 3;
  int g = xcd * (2 * Bc) + slot / 6;
  int cx = slot % 6;
  int bl = g >> 4, my = g & 15;
  int m0 = my * 64, c0 = cx * 128;
  int t0 = cx * 4;
  int tid = threadIdx.x;
  int lane = tid & 63, w = tid >> 6;
  int l15 = lane & 15, quad = lane >> 4;
  int wmi = w & 1, wci = w >> 1;
  int rl = lane >> 2;                               // staging row-within-16
  int ch = (lane & 3) ^ ((rl ^ (rl >> 2)) & 3);     // pre-swz source chunk
  int kq = (quad ^ ((l15 ^ (l15 >> 2)) & 3)) * 8;   // read chunk offset

  f32x4 acc[3][2][4];
  #pragma unroll
  for (int k = 0; k < 3; ++k)
    #pragma unroll
    for (int mt = 0; mt < 2; ++mt)
      #pragma unroll
      for (int ct = 0; ct < 4; ++ct) acc[k][mt][ct] = (f32x4){0.f, 0.f, 0.f, 0.f};

  auto STAGE = [&](unsigned short* Ab, unsigned short* Xb, int n0s) {
    #pragma unroll
    for (int it = 0; it < 3; ++it) {                // A: 12 x 16-row writes
      int i = w * 3 + it;
      int k = i >> 2;
      int mrow = (i & 3) * 16 + rl;
      gload16(&Abf[((size_t)(k * Bc + bl) * N + m0 + mrow) * N + n0s + ch * 8],
              Ab + i * 512);
    }
    #pragma unroll
    for (int it = 0; it < 2; ++it) {                // X: 8 x 16-row writes
      int i = w * 2 + it;
      int crow = i * 16 + rl;
      gload16(&xT[((size_t)bl * FT + c0 + crow) * N + n0s + ch * 8],
              Xb + i * 512);
    }
  };
  auto COMPUTE = [&](const unsigned short* Ab, const unsigned short* Xb) {
    short8 bfr[4];
    #pragma unroll
    for (int ct = 0; ct < 4; ++ct) {
      int row = wci * 64 + ct * 16 + l15;
      bfr[ct] = *(const short8*)&Xb[row * 32 + kq];
    }
    #pragma unroll
    for (int k = 0; k < 3; ++k)
      #pragma unroll
      for (int mt = 0; mt < 2; ++mt) {
        int row = k * 64 + wmi * 32 + mt * 16 + l15;
        short8 af = *(const short8*)&Ab[row * 32 + kq];
        #pragma unroll
        for (int ct = 0; ct < 4; ++ct)
          acc[k][mt][ct] = __builtin_amdgcn_mfma_f32_16x16x32_bf16(
              af, bfr[ct], acc[k][mt][ct], 0, 0, 0);
      }
  };

  STAGE(A0, X0, 0);
  __syncthreads();
  for (int n0 = 0; n0 < N; n0 += 64) {
    STAGE(A1, X1, n0 + 32);
    COMPUTE(A0, X0);
    __syncthreads();
    if (n0 + 64 < N) STAGE(A0, X0, n0 + 64);
    COMPUTE(A1, X1);
    __syncthreads();
  }

  // ---- theta epilogue (r13 full form) ----
  short8 bth[4][3];
  #pragma unroll
  for (int ot = 0; ot < 4; ++ot)
    #pragma unroll
    for (int ks = 0; ks < 3; ++ks)
      bth[ot][ks] = *(const short8*)&wbf[(ot * 16 + l15) * 96 + ks * 32 + quad * 8];

  // acc -> A_th[rho=(m_local*4+t_local)][kf=k*32+f] bf16
  #pragma unroll
  for (int k = 0; k < 3; ++k)
    #pragma unroll
    for (int mt = 0; mt < 2; ++mt)
      #pragma unroll
      for (int ct = 0; ct < 4; ++ct) {
        int tl = wci * 2 + (ct >> 1);
        int f  = (ct & 1) * 16 + l15;
        #pragma unroll
        for (int r = 0; r < 4; ++r) {
          int mloc = wmi * 32 + mt * 16 + quad * 4 + r;
          A_th[(mloc * 4 + tl) * 104 + k * 32 + f] = f2bu(acc[k][mt][ct][r]);
        }
      }
  __syncthreads();

  // theta MFMA: wave w -> M-tiles w*4..w*4+3 (rows rho), all 4 o-tiles.
  #pragma unroll
  for (int i = 0; i < 4; ++i) {
    short8 af[3];
    #pragma unroll
    for (int ks = 0; ks < 3; ++ks)
      af[ks] = *(const short8*)&A_th[((w * 4 + i) * 16 + l15) * 104 + ks * 32 + quad * 8];
    int mloc = (w * 4 + i) * 4 + quad;     // rho>>2 for this lane's C rows
    size_t base = ((size_t)(bl * N + m0 + mloc)) * (T * CC) + (size_t)t0 * CC;
    #pragma unroll
    for (int ot = 0; ot < 4; ++ot) {
      f32x4 th = (f32x4){0.f, 0.f, 0.f, 0.f};
      #pragma unroll
      for (int ks = 0; ks < 3; ++ks)
        th = __builtin_amdgcn_mfma_f32_16x16x32_bf16(af[ks], bth[ot][ks], th, 0, 0, 0);
      #pragma unroll
      for (int rr = 0; rr < 4; ++rr)       // rho&3 = rr -> t = t0+rr
        sg[base + (size_t)rr * CC + ot * 16 + l15] = f2bu(fmaxf(th[rr], 0.f));
    }
  }
}

// ---------------- tail: conv (MFMA) + residual + LN -------------------------
__global__ __launch_bounds__(256) void k_tail(const unsigned short* sg,
                                              const float* x,
                                              const unsigned short* wbf,
                                              const float* tcb, const float* rcb,
                                              const float* gam, const float* bet,
                                              float* out, int b0) {
  __shared__ __align__(16) unsigned char smem[38272];
  float* co_l = (float*)(smem + 13312);             // [96][65] f32
  int tid = threadIdx.x;
  int w = tid >> 6, lane = tid & 63;
  int l15 = lane & 15, quad = lane >> 4;
  int r0l = blockIdx.x * 4;
  int o0 = w * 16;

  short8 btc[6];
  {
    int o = o0 + l15;
    #pragma unroll
    for (int s = 0; s < 6; ++s)
      btc[s] = *(const short8*)&wbf[6144 + o * 192 + s * 32 + quad * 8];
  }

  // P0: zero pad rows + stage sg -> sg_l[m][t'][cc] (XOR-swz (rp&7)<<4,
  // 16B-chunk granular so uint4 copies preserve the swizzle).
  if (tid < 64) {
    int m = tid >> 4, rr = (tid >> 3) & 1, ck = tid & 7;
    int rp = m * 26 + rr * 25;
    *(uint4*)(smem + rp * 128 + ((ck * 16) ^ ((rp & 7) << 4))) =
        make_uint4(0, 0, 0, 0);
  }
  #pragma unroll
  for (int it = 0; it < 3; ++it) {       // 768 chunks of 16B
    int ch = it * 256 + tid;
    int m = ch / 192, rem = ch % 192;
    int t = rem >> 3, ck = rem & 7;
    uint4 v = *(const uint4*)&sg[((size_t)(r0l + m)) * (T * CC) + t * CC + ck * 8];
    int rp = m * 26 + t + 1;
    *(uint4*)(smem + rp * 128 + ((ck * 16) ^ ((rp & 7) << 4))) = v;
  }
  __syncthreads();

  // conv MFMA, K = 192 (j*64+cc); A row (m,t) col j*64+cc = sg[m][t+j][cc].
  f32x4 cv[6];
  #pragma unroll
  for (int Mt = 0; Mt < 6; ++Mt) {
    int row = Mt * 16 + l15;
    int m = row / 24, t = row % 24;
    cv[Mt] = (f32x4){0.f, 0.f, 0.f, 0.f};
    #pragma unroll
    for (int s = 0; s < 6; ++s) {
      int rp = m * 26 + t + (s >> 1);
      int cb = (32 * (s & 1) + quad * 8) * 2;
      short8 af = *(const short8*)(smem + rp * 128 + (cb ^ ((rp & 7) << 4)));
      cv[Mt] = __builtin_amdgcn_mfma_f32_16x16x32_bf16(af, btc[s], cv[Mt], 0, 0, 0);
    }
  }
  #pragma unroll
  for (int Mt = 0; Mt < 6; ++Mt)
    #pragma unroll
    for (int r = 0; r < 4; ++r) {
      int row = Mt * 16 + quad * 4 + r;
      co_l[row * 65 + o0 + l15] = cv[Mt][r];
    }
  __syncthreads();

  // per-lane o; bias + residual (fp32) + relu + LN + store.
  int o = lane;
  float bias = tcb[o] + rcb[o];
  float acc[T];
  #pragma unroll
  for (int t = 0; t < T; ++t) acc[t] = co_l[(w * 24 + t) * 65 + o] + bias;

  size_t grow = (size_t)b0 * N + r0l + w;
  const float* xrow = x + grow * FT;
  const unsigned* rcp = (const unsigned*)(wbf + 18432);
  #pragma unroll 4
  for (int f2 = 0; f2 < 16; ++f2) {
    unsigned u = rcp[f2 * 64 + o];
    float wf0 = us2f((unsigned short)(u & 0xffffu));
    float wf1 = us2f((unsigned short)(u >> 16));
    const float4* xp0 = (const float4*)&xrow[(f2 * 2) * 24];     // wave-uniform
    const float4* xp1 = (const float4*)&xrow[(f2 * 2 + 1) * 24]; // broadcast
    #pragma unroll
    for (int q = 0; q < 6; ++q) {
      float4 v0 = xp0[q], v1 = xp1[q];
      acc[q * 4 + 0] += wf0 * v0.x + wf1 * v1.x;
      acc[q * 4 + 1] += wf0 * v0.y + wf1 * v1.y;
      acc[q * 4 + 2] += wf0 * v0.z + wf1 * v1.z;
      acc[q * 4 + 3] += wf0 * v0.w + wf1 * v1.w;
    }
  }
  float g = gam[o], be = bet[o];
  #pragma unroll
  for (int t = 0; t < T; ++t) {
    float z = fmaxf(acc[t], 0.f);
    float s = z, q = z * z;
    #pragma unroll
    for (int off = 1; off < 64; off <<= 1) {
      s += __shfl_xor(s, off);
      q += __shfl_xor(q, off);
    }
    float mu = s * (1.f / 64.f);
    float var = q * (1.f / 64.f) - mu * mu;
    acc[t] = (z - mu) * rsqrtf(var + 1e-5f) * g + be;
  }
  float* orow = out + grow * CTT + o * T;
  #pragma unroll
  for (int q = 0; q < 6; ++q)
    ((float4*)orow)[q] =
        make_float4(acc[q * 4], acc[q * 4 + 1], acc[q * 4 + 2], acc[q * 4 + 3]);
}

}  // namespace

extern "C" void kernel_launch(void* const* d_in, const int* in_sizes, int n_in,
                              void* d_out, int out_size, void* d_ws, size_t ws_size,
                              hipStream_t stream) {
  (void)in_sizes; (void)n_in; (void)out_size;
  const float* x     = (const float*)d_in[0];
  const float* W1    = (const float*)d_in[1];
  const float* W2    = (const float*)d_in[2];
  const float* W3    = (const float*)d_in[3];
  const float* U1    = (const float*)d_in[4];
  const float* U2    = (const float*)d_in[5];
  const float* U3    = (const float*)d_in[6];
  const float* cheb  = (const float*)d_in[7];
  const float* Theta = (const float*)d_in[8];
  const float* tcw   = (const float*)d_in[9];
  const float* tcb   = (const float*)d_in[10];
  const float* rcw   = (const float*)d_in[11];
  const float* rcb   = (const float*)d_in[12];
  const float* gam   = (const float*)d_in[13];
  const float* bet   = (const float*)d_in[14];
  float* out = (float*)d_out;

  // ---- runtime-adaptive workspace layout ----
  const size_t SB_BYTES = (size_t)B * N * N * 2;          // 33,554,432 (S bf16)
  const size_t WB_BYTES = 65536;                          // wbf (40960 used)
  const size_t AB_PER_B = (size_t)3 * N * N * 2;          // 6,291,456
  const size_t XT_PER_B = (size_t)FT * N * 2;             // 1,572,864
  const size_t SG_PER_B = (size_t)N * T * CC * 2;         // 3,145,728
  const size_t SMALL = 2816384 * 4;                       // 11,265,536 B
  int Bc = 16;
  while (Bc > 1 && SB_BYTES + WB_BYTES + SMALL +
             (size_t)Bc * (AB_PER_B + XT_PER_B + SG_PER_B) > ws_size)
    Bc >>= 1;

  char* w = (char*)d_ws;
  __hip_bfloat16* Sb = (__hip_bfloat16*)w;
  unsigned short* wbf = (unsigned short*)(w + SB_BYTES);
  unsigned short* Abf = (unsigned short*)(w + SB_BYTES + WB_BYTES);
  unsigned short* xTb = (unsigned short*)(w + SB_BYTES + WB_BYTES +
                                          (size_t)Bc * AB_PER_B);
  unsigned short* sgb = (unsigned short*)(w + SB_BYTES + WB_BYTES +
                                          (size_t)Bc * (AB_PER_B + XT_PER_B));
  float* sm = (float*)(w + SB_BYTES + WB_BYTES +
                       (size_t)Bc * (AB_PER_B + XT_PER_B + SG_PER_B));
  float* lhst = sm;                       // B*T*F   = 12288
  float* lhs2 = lhst + B * T * F;         // B*T*N   = 393216
  float* rhst = lhs2 + B * T * N;         // B*N*T   = 393216
  float* w3x  = rhst + B * N * T;         // B*N*T   = 393216
  float* Elog = w3x + B * N * T;          // B*T*T   = 9216
  float* E    = Elog + B * T * T;         // B*T*T   = 9216
  float* EW1  = E + B * T * T;            // B*T     = 384
  float* tmp1 = EW1 + B * T;              // B*N*F   = 524288
  float* lhss = tmp1 + B * N * F;         // B*N*T   = 393216
  float* rhss = lhss + B * N * T;         // B*N*T   = 393216
  float* pmx  = rhss + B * N * T;         // NSEG*B*N = 131072
  float* psm  = pmx + NSEG * B * N;       // NSEG*B*N = 131072
  float* smax = psm + NSEG * B * N;       // B*N     = 16384
  float* sinv = smax + B * N;             // B*N     = 16384

  // temporal attention
  k_lhs_t<<<B * T * F, 64, 0, stream>>>(x, U1, lhst);
  k_lhs2<<<(B * T * N) / 256, 256, 0, stream>>>(lhst, U2, lhs2);
  k_fx<<<(B * N * T) / 256, 256, 0, stream>>>(x, U3, W3, rhst, w3x);
  k_Elog<<<B * T * T, 64, 0, stream>>>(lhs2, rhst, Elog);
  k_EsmW1<<<B, 64, 0, stream>>>(Elog, W1, E, EW1);

  // spatial attention (x_TAt folded out)
  k_tmp1x<<<(B * N * F) / 256, 256, 0, stream>>>(x, EW1, tmp1);
  k_lhs_s<<<(B * N * T) / 256, 256, 0, stream>>>(tmp1, W2, lhss);
  k_rhss<<<(B * N * T) / 256, 256, 0, stream>>>(w3x, E, rhss);
  k_Slog<<<dim3(N / 256, N / 16, B), 256, 0, stream>>>(lhss, rhss, Sb);
  k_Ssum<<<dim3(N / 128, B, NSEG), 256, 0, stream>>>(Sb, pmx, psm);
  k_Scomb<<<(B * N) / 256, 256, 0, stream>>>(pmx, psm, smax, sinv);

  // weight prep (once)
  k_prepW<<<1, 256, 0, stream>>>(Theta, tcw, rcw, wbf);

  // per-chunk: operand prep + fused GEMM(+theta) + tail epilogue
  for (int b0 = 0; b0 < B; b0 += Bc) {
    k_prepA<<<dim3(N / 64, N / 64, 3 * Bc), 256, 0, stream>>>(cheb, Sb, smax,
                                                              sinv, Abf, Bc, b0);
    k_prepX<<<dim3(N / 64, FT / 64, Bc), 256, 0, stream>>>(x, xTb, b0);
    k_gemm3<<<dim3(96 * Bc), 256, 0, stream>>>(Abf, xTb, wbf, sgb, Bc);
    k_tail<<<Bc * N / 4, 256, 0, stream>>>(sgb, x, wbf, tcb, rcb,
                                           gam, bet, out, b0);
  }
}